// Round 1
// 288.997 us; speedup vs baseline: 1.0429x; 1.0429x over previous
//
#include <hip/hip_runtime.h>
#include <hip/hip_bf16.h>
#include <stdint.h>

typedef __hip_bfloat16 bf16;
typedef __attribute__((ext_vector_type(8))) short short8;
typedef __attribute__((ext_vector_type(4))) float f32x4;
typedef __attribute__((ext_vector_type(16))) float f32x16;

#define MFMA16(a, b, c) __builtin_amdgcn_mfma_f32_16x16x32_bf16(a, b, c, 0, 0, 0)
#define MFMA32(a, b, c) __builtin_amdgcn_mfma_f32_32x32x16_bf16(a, b, c, 0, 0, 0)

#define BATCH 8
#define SEQ   1024
#define DEMB  1024
#define NH    16
#define DH    64
#define MTOT  (BATCH * SEQ)   // 8192

// ---------------------------------------------------------------------------
// dtype helpers: flag==1 -> input buffers are float32; flag==0 -> bf16.
// ---------------------------------------------------------------------------
__device__ __forceinline__ float rdf(const void* p, size_t idx, int isf) {
  if (isf) return ((const float*)p)[idx];
  return __bfloat162float(((const bf16*)p)[idx]);
}

// pack two f32 -> bf16x2 dword
__device__ __forceinline__ unsigned int pk2(float a, float b) {
  unsigned short ua = __bfloat16_as_ushort(__float2bfloat16(a));
  unsigned short ub = __bfloat16_as_ushort(__float2bfloat16(b));
  return (unsigned int)ua | ((unsigned int)ub << 16);
}

union U4S8 { uint4 u; short8 s; };

// async global->LDS, 16B per lane; lds base wave-uniform (HW adds lane*16)
__device__ __forceinline__ void gload16(const bf16* g, bf16* l) {
  __builtin_amdgcn_global_load_lds(
      (const __attribute__((address_space(1))) void*)g,
      (__attribute__((address_space(3))) void*)l, 16, 0, 0);
}

// Kernel 0: detect input dtype from x.
__global__ void detect_dtype(const unsigned int* __restrict__ xw, int* __restrict__ flag) {
  int lane = threadIdx.x;  // 64 threads
  float v = __uint_as_float(xw[lane]);
  bool isf32 = (fabsf(v) < 1e20f);  // NaN/Inf -> false
  unsigned long long m = __ballot(isf32);
  if (lane == 0) flag[0] = (__popcll(m) >= 32) ? 1 : 0;
}

// Kernel 0b: canonicalize x -> bf16 xc[8192][1024]. 8 elems/thread.
__global__ __launch_bounds__(256) void convert_x(
    const void* __restrict__ xin, bf16* __restrict__ xc, const int* __restrict__ flag) {
  const int isf = flag[0];
  size_t i = ((size_t)blockIdx.x * 256 + threadIdx.x) * 8;
  if (isf) {
    const float* xf = (const float*)xin;
    float4 a = *(const float4*)&xf[i];
    float4 b = *(const float4*)&xf[i + 4];
    bf16 o[8];
    o[0] = __float2bfloat16(a.x); o[1] = __float2bfloat16(a.y);
    o[2] = __float2bfloat16(a.z); o[3] = __float2bfloat16(a.w);
    o[4] = __float2bfloat16(b.x); o[5] = __float2bfloat16(b.y);
    o[6] = __float2bfloat16(b.z); o[7] = __float2bfloat16(b.w);
    *(int4*)&xc[i] = *(const int4*)&o[0];
  } else {
    *(int4*)&xc[i] = *(const int4*)&((const bf16*)xin)[i];
  }
}

// ---------------------------------------------------------------------------
// Kernel 1: permute+transpose w_qkv -> wt [3072][1024]; bias -> f32 bqp.
// ---------------------------------------------------------------------------
__global__ __launch_bounds__(256) void permute_wqkv(
    const void* __restrict__ w, const void* __restrict__ b,
    bf16* __restrict__ wt, float* __restrict__ bqp, const int* __restrict__ flag) {
  __shared__ __attribute__((aligned(16))) bf16 ls[192][66];
  const int isf = flag[0];
  const int t = threadIdx.x;
  const int k0 = blockIdx.x * 64;
  const int h = blockIdx.y;
#pragma unroll
  for (int i = 0; i < 48; ++i) {
    int e = t + i * 256;
    int k = e / 192, c = e % 192;
    ls[c][k] = __float2bfloat16(rdf(w, (size_t)(k0 + k) * 3072 + h * 192 + c, isf));
  }
  if (blockIdx.x == 0 && t < 192) {
    int dd = t / 3, j = t % 3;
    bqp[j * 1024 + h * 64 + dd] = rdf(b, h * 192 + t, isf);
  }
  __syncthreads();
#pragma unroll
  for (int i = 0; i < 48; ++i) {
    int e = t + i * 256;
    int c = e / 64, k = e & 63;
    int dd = c / 3, j = c % 3;
    wt[(size_t)(j * 1024 + h * 64 + dd) * 1024 + k0 + k] = ls[c][k];
  }
}

// ---------------------------------------------------------------------------
// Kernel 2: transpose w_proj [1024][1024] -> wtp [n][k]
// ---------------------------------------------------------------------------
__global__ __launch_bounds__(256) void transpose_wp(
    const void* __restrict__ w, bf16* __restrict__ wt, const int* __restrict__ flag) {
  __shared__ __attribute__((aligned(16))) bf16 ls[64][66];
  const int isf = flag[0];
  const int t = threadIdx.x;
  const int r0 = blockIdx.y * 64;
  const int c0 = blockIdx.x * 64;
#pragma unroll
  for (int i = 0; i < 16; ++i) {
    int e = t + i * 256;
    int r = e >> 6, c = e & 63;
    ls[c][r] = __float2bfloat16(rdf(w, (size_t)(r0 + r) * 1024 + c0 + c, isf));
  }
  __syncthreads();
#pragma unroll
  for (int i = 0; i < 16; ++i) {
    int e = t + i * 256;
    int c = e >> 6, r = e & 63;
    wt[(size_t)(c0 + c) * 1024 + r0 + r] = ls[c][r];
  }
}

// ---------------------------------------------------------------------------
// 256x256 deep-pipelined GEMM core (T3+T4+T5 schedule, plain HIP).
// C[256x256] at (m0,n0) = A[m0..][1024] * Bt[n0..][1024]^T, K=1024.
// 8 waves (2M x 4N), per-wave C = 128x64 = acc[8][4] f32x4.
// BK=32. LDS ring: 4 slots x (A[256][32] + B[256][32]) = 128 KiB (dynamic).
// Rows are 64B -> [16][32] subtile reads are naturally bank-balanced; LDS
// stays linear so global_load_lds (wave-uniform dest + lane*16) works.
// Per K-tile: 2 phases x {ds_read frags; issue 2 gload_lds for tile tau+3;
// raw s_barrier; lgkmcnt(0); setprio(1); 16 MFMA; setprio(0); barrier}.
// s_waitcnt vmcnt(8) ONCE per K-tile boundary: at that point the in-flight
// queue is [tau+1's 4, tau+2's 4, tau+3's 4] -> vmcnt(8) drains exactly
// tau+1 (needed next), keeps 2 K-tiles (8 loads) in flight. Never vmcnt(0)
// in the loop; vmcnt(0) once after it (also fences epilogue global loads
// out of the vmcnt ledger).
// ---------------------------------------------------------------------------
__device__ __forceinline__ void gemm256_core(
    const bf16* __restrict__ A, const bf16* __restrict__ Bt,
    int m0, int n0, bf16* lds, f32x4 acc[8][4]) {
  const int t = threadIdx.x;
  const int lane = t & 63, w = t >> 6;
  const int l15 = lane & 15, quad = lane >> 4;
  const int wm = w >> 2, wn = w & 3;

  // staging: wave w writes subtile w (half0) / 8+w (half1); lane covers 16B:
  // row (lane>>2) within subtile, cols (lane&3)*8 .. +8
  const int sr = lane >> 2;
  const int sc = (lane & 3) * 8;
  const bf16* gA = A + (size_t)(m0 + w * 16 + sr) * 1024 + sc;   // half1 = +128 rows
  const bf16* gB = Bt + (size_t)(n0 + w * 16 + sr) * 1024 + sc;

  // prologue: stage K-tiles 0,1,2 into slots 0,1,2 (A.h0,A.h1,B.h0,B.h1 each)
#pragma unroll
  for (int tt = 0; tt < 3; ++tt) {
    bf16* sb = lds + tt * 16384;
    gload16(gA + tt * 32, sb + w * 512);
    gload16(gA + tt * 32 + 131072, sb + 4096 + w * 512);
    gload16(gB + tt * 32, sb + 8192 + w * 512);
    gload16(gB + tt * 32 + 131072, sb + 12288 + w * 512);
  }
  asm volatile("s_waitcnt vmcnt(8)" ::: "memory");  // tile 0 landed; 1,2 in flight
  __builtin_amdgcn_s_barrier();

#pragma unroll 4
  for (int tau = 0; tau < 32; ++tau) {
    const int slot = tau & 3;
    const int pf = (tau + 3) & 3;                 // slot freed at end of tau-1
    const int kpf = ((tau + 3) & 31) * 32;        // wrap tail prefetch in-bounds
    const bf16* ls = lds + slot * 16384;
    bf16* sb = lds + pf * 16384;

    short8 afr[4], bfr[4];
    // ---- phase 0: fi 0..3, all fj ----
    const bf16* pa0 = ls + (wm * 128 + l15) * 32 + quad * 8;
#pragma unroll
    for (int i = 0; i < 4; ++i) afr[i] = *(const short8*)(pa0 + i * 512);
    const bf16* pb0 = ls + 8192 + (wn * 64 + l15) * 32 + quad * 8;
#pragma unroll
    for (int j = 0; j < 4; ++j) bfr[j] = *(const short8*)(pb0 + j * 512);
    gload16(gA + kpf, sb + w * 512);
    gload16(gA + kpf + 131072, sb + 4096 + w * 512);
    asm volatile("" ::: "memory");
    __builtin_amdgcn_s_barrier();
    asm volatile("s_waitcnt lgkmcnt(0)" ::: "memory");
    __builtin_amdgcn_s_setprio(1);
#pragma unroll
    for (int i = 0; i < 4; ++i)
#pragma unroll
      for (int j = 0; j < 4; ++j)
        acc[i][j] = MFMA16(afr[i], bfr[j], acc[i][j]);
    __builtin_amdgcn_s_setprio(0);
    asm volatile("" ::: "memory");
    __builtin_amdgcn_s_barrier();

    // ---- phase 1: fi 4..7, reuse bfr ----
    const bf16* pa1 = pa0 + 64 * 32;
#pragma unroll
    for (int i = 0; i < 4; ++i) afr[i] = *(const short8*)(pa1 + i * 512);
    gload16(gB + kpf, sb + 8192 + w * 512);
    gload16(gB + kpf + 131072, sb + 12288 + w * 512);
    asm volatile("" ::: "memory");
    __builtin_amdgcn_s_barrier();
    asm volatile("s_waitcnt lgkmcnt(0)" ::: "memory");
    __builtin_amdgcn_s_setprio(1);
#pragma unroll
    for (int i = 0; i < 4; ++i)
#pragma unroll
      for (int j = 0; j < 4; ++j)
        acc[4 + i][j] = MFMA16(afr[i], bfr[j], acc[4 + i][j]);
    __builtin_amdgcn_s_setprio(0);
    asm volatile("s_waitcnt vmcnt(8)" ::: "memory");  // K-tile boundary: tau+1 landed
    asm volatile("" ::: "memory");
    __builtin_amdgcn_s_barrier();
  }
  asm volatile("s_waitcnt vmcnt(0)" ::: "memory");    // drain leftovers before exit
}

// ---------------------------------------------------------------------------
// Kernel 3: QKV GEMM (256^2 core). Scatters q,k -> [b][h][n][dd]; v -> [b][h][dd][n].
// grid 384 = (8192/256) x (3072/256), XCD-bijective swizzle (384 % 8 == 0).
// ---------------------------------------------------------------------------
__global__ __launch_bounds__(512, 2) void gemm256_qkv(
    const bf16* __restrict__ A, const bf16* __restrict__ Bt,
    const float* __restrict__ bias,
    bf16* __restrict__ qb, bf16* __restrict__ kb, bf16* __restrict__ vb) {
  extern __shared__ bf16 smem[];
  const int t = threadIdx.x;
  const int lane = t & 63;
  const int l15 = lane & 15, quad = lane >> 4;
  const int w = t >> 6, wm = w >> 2, wn = w & 3;
  const int bid = blockIdx.x;
  const int swz = (bid & 7) * 48 + (bid >> 3);   // 384/8 = 48 per XCD
  const int m0 = (swz / 12) * 256;
  const int n0 = (swz % 12) * 256;

  f32x4 acc[8][4];
  const f32x4 zero = {0.f, 0.f, 0.f, 0.f};
#pragma unroll
  for (int i = 0; i < 8; ++i)
#pragma unroll
    for (int j = 0; j < 4; ++j) acc[i][j] = zero;

  gemm256_core(A, Bt, m0, n0, smem, acc);

  const int jj = n0 >> 10;                       // 0=q 1=k 2=v (256-tile within chunk)
  const int hh = ((n0 + wn * 64) & 1023) >> 6;   // head: uniform per wave
#pragma unroll
  for (int fi = 0; fi < 8; ++fi) {
    int m = m0 + wm * 128 + fi * 16 + quad * 4;
    int bb = m >> 10, nidx = m & 1023;
    size_t bhq = (size_t)(bb * NH + hh);
#pragma unroll
    for (int fj = 0; fj < 4; ++fj) {
      int dd = fj * 16 + l15;
      float bv = bias[n0 + wn * 64 + dd];
      if (jj == 2) {
        // v: [b][h][dd][n] -> 4 consecutive n pack into 8B
        unsigned int lo = pk2(acc[fi][fj][0] + bv, acc[fi][fj][1] + bv);
        unsigned int hi = pk2(acc[fi][fj][2] + bv, acc[fi][fj][3] + bv);
        *(uint2*)&vb[(bhq * 64 + dd) * 1024 + nidx] = make_uint2(lo, hi);
      } else {
        bf16* dst = (jj == 0) ? qb : kb;
#pragma unroll
        for (int r = 0; r < 4; ++r)
          dst[(bhq * 1024 + (size_t)(nidx + r)) * 64 + dd] =
              __float2bfloat16(acc[fi][fj][r] + bv);
      }
    }
  }
}

// ---------------------------------------------------------------------------
// Kernel 4 v2: flash attention with 32x32x16 MFMA, S^T/O^T formulation.
// ---------------------------------------------------------------------------
__global__ __launch_bounds__(256, 4) void attn(
    const bf16* __restrict__ qb, const bf16* __restrict__ kb,
    const bf16* __restrict__ vb, bf16* __restrict__ ob) {
  const int t = threadIdx.x, lane = t & 63, w = t >> 6;
  const int q5 = lane & 31, half = lane >> 5;
  const int bh = blockIdx.y;
  const int bat = bh >> 4, h = bh & 15;
  const int q0 = blockIdx.x * 128;
  const int qrow = q0 + w * 32 + q5;

  __shared__ __attribute__((aligned(16))) bf16 lsK[64][72];  // 9216 B
  __shared__ __attribute__((aligned(16))) bf16 lsV[64][72];  // 9216 B

  const bf16* qp = qb + (size_t)bh * (1024 * 64);
  const bf16* kp = kb + (size_t)bh * (1024 * 64);
  const bf16* vp = vb + (size_t)bh * (64 * 1024);  // [dv][n]

  short8 bq[4];
#pragma unroll
  for (int kk = 0; kk < 4; ++kk)
    bq[kk] = *(const short8*)&qp[(size_t)qrow * 64 + kk * 16 + half * 8];

  float m_run = -1e30f, l_run = 0.f;
  f32x16 po[2];
#pragma unroll
  for (int r = 0; r < 16; ++r) { po[0][r] = 0.f; po[1][r] = 0.f; }

  const int sr = t >> 3;        // 0..31
  const int sc = (t & 7) * 8;   // 0..56

  for (int kt = 0; kt < 1024; kt += 64) {
    int4 g0 = *(const int4*)&kp[(size_t)(kt + sr) * 64 + sc];
    int4 g1 = *(const int4*)&kp[(size_t)(kt + 32 + sr) * 64 + sc];
    int4 g2 = *(const int4*)&vp[(size_t)sr * 1024 + kt + sc];
    int4 g3 = *(const int4*)&vp[(size_t)(32 + sr) * 1024 + kt + sc];
    __syncthreads();
    *(int4*)&lsK[sr][sc] = g0;
    *(int4*)&lsK[32 + sr][sc] = g1;
    *(int4*)&lsV[sr][sc] = g2;
    *(int4*)&lsV[32 + sr][sc] = g3;
    __syncthreads();

    f32x16 st[2];
#pragma unroll
    for (int r = 0; r < 16; ++r) { st[0][r] = 0.f; st[1][r] = 0.f; }
#pragma unroll
    for (int kk = 0; kk < 4; ++kk) {
#pragma unroll
      for (int tj = 0; tj < 2; ++tj) {
        short8 ak = *(const short8*)&lsK[tj * 32 + q5][kk * 16 + half * 8];
        st[tj] = MFMA32(ak, bq[kk], st[tj]);
      }
    }

    float smax = st[0][0];
#pragma unroll
    for (int r = 1; r < 16; ++r) smax = fmaxf(smax, st[0][r]);
#pragma unroll
    for (int r = 0; r < 16; ++r) smax = fmaxf(smax, st[1][r]);
    smax = fmaxf(smax, __shfl_xor(smax, 32));
    float mnew = fmaxf(m_run, smax);
    float alpha = __expf(m_run - mnew);
    m_run = mnew;
    float lsum = 0.f;
#pragma unroll
    for (int tj = 0; tj < 2; ++tj)
#pragma unroll
      for (int r = 0; r < 16; ++r) {
        float p = __expf(st[tj][r] - mnew);
        st[tj][r] = p;
        lsum += p;
      }
    lsum += __shfl_xor(lsum, 32);
    l_run = l_run * alpha + lsum;
#pragma unroll
    for (int r = 0; r < 16; ++r) { po[0][r] *= alpha; po[1][r] *= alpha; }

#pragma unroll
    for (int kk2 = 0; kk2 < 4; ++kk2) {
      const int nbA = 2 * kk2, nbB = 2 * kk2 + 1;
      unsigned int a0 = pk2(st[nbA >> 2][4 * (nbA & 3) + 0], st[nbA >> 2][4 * (nbA & 3) + 1]);
      unsigned int a1 = pk2(st[nbA >> 2][4 * (nbA & 3) + 2], st[nbA >> 2][4 * (nbA & 3) + 3]);
      unsigned int b0 = pk2(st[nbB >> 2][4 * (nbB & 3) + 0], st[nbB >> 2][4 * (nbB & 3) + 1]);
      unsigned int b1 = pk2(st[nbB >> 2][4 * (nbB & 3) + 2], st[nbB >> 2][4 * (nbB & 3) + 3]);
      unsigned int s0 = half ? a0 : b0;
      unsigned int s1 = half ? a1 : b1;
      unsigned int r0 = (unsigned int)__shfl_xor((int)s0, 32);
      unsigned int r1 = (unsigned int)__shfl_xor((int)s1, 32);
      U4S8 fr;
      fr.u.x = half ? r0 : a0;
      fr.u.y = half ? r1 : a1;
      fr.u.z = half ? b0 : r0;
      fr.u.w = half ? b1 : r1;
#pragma unroll
      for (int ti = 0; ti < 2; ++ti) {
        short8 av = *(const short8*)&lsV[ti * 32 + q5][kk2 * 16 + half * 8];
        po[ti] = MFMA32(av, fr.s, po[ti]);
      }
    }
  }

  float inv = 1.0f / (l_run * 32.0f);
  bf16* op = ob + ((size_t)(bat * 1024 + qrow)) * 1024 + h * 64;
#pragma unroll
  for (int ti = 0; ti < 2; ++ti)
#pragma unroll
    for (int g = 0; g < 4; ++g) {
      unsigned int lo = pk2(po[ti][4 * g + 0] * inv, po[ti][4 * g + 1] * inv);
      unsigned int hi = pk2(po[ti][4 * g + 2] * inv, po[ti][4 * g + 3] * inv);
      uint2 u = make_uint2(lo, hi);
      *(uint2*)&op[ti * 32 + g * 8 + half * 4] = u;
    }
}

// ---------------------------------------------------------------------------
// Kernel 5: output projection (256^2 core). OUTPUT: float32.
// grid 128 = (8192/256) x (1024/256), XCD-bijective swizzle (128 % 8 == 0).
// ---------------------------------------------------------------------------
__global__ __launch_bounds__(512, 2) void gemm256_proj(
    const bf16* __restrict__ A, const bf16* __restrict__ Bt,
    const void* __restrict__ bias, float* __restrict__ out,
    const int* __restrict__ flag) {
  extern __shared__ bf16 smem[];
  const int t = threadIdx.x;
  const int lane = t & 63;
  const int l15 = lane & 15, quad = lane >> 4;
  const int w = t >> 6, wm = w >> 2, wn = w & 3;
  const int bid = blockIdx.x;
  const int swz = (bid & 7) * 16 + (bid >> 3);   // 128/8 = 16 per XCD
  const int m0 = (swz >> 2) * 256;
  const int n0 = (swz & 3) * 256;

  f32x4 acc[8][4];
  const f32x4 zero = {0.f, 0.f, 0.f, 0.f};
#pragma unroll
  for (int i = 0; i < 8; ++i)
#pragma unroll
    for (int j = 0; j < 4; ++j) acc[i][j] = zero;

  gemm256_core(A, Bt, m0, n0, smem, acc);

  const int isf = flag[0];
#pragma unroll
  for (int fj = 0; fj < 4; ++fj) {
    int c = n0 + wn * 64 + fj * 16 + l15;
    float bv = rdf(bias, c, isf);
#pragma unroll
    for (int fi = 0; fi < 8; ++fi) {
      int m = m0 + wm * 128 + fi * 16 + quad * 4;
#pragma unroll
      for (int r = 0; r < 4; ++r)
        out[(size_t)(m + r) * 1024 + c] = acc[fi][fj][r] + bv;
    }
  }
}

// ---------------------------------------------------------------------------
// Launcher. ws layout (75.5 MB):
//   wt_qkv 6MB | bqp 12KB | wtp 2MB | xc/att 16MB | q 16MB | k 16MB | v 16MB | flag
// ---------------------------------------------------------------------------
extern "C" void kernel_launch(void* const* d_in, const int* in_sizes, int n_in,
                              void* d_out, int out_size, void* d_ws, size_t ws_size,
                              hipStream_t stream) {
  const void* x      = d_in[0];
  const void* w_qkv  = d_in[1];
  const void* b_qkv  = d_in[2];
  const void* w_proj = d_in[3];
  const void* b_proj = d_in[4];
  float* out = (float*)d_out;

  char* ws = (char*)d_ws;
  bf16*  wt_qkv = (bf16*)(ws);
  float* bqp    = (float*)(ws + 6291456);
  bf16*  wtp    = (bf16*)(ws + 6303744);
  bf16*  xc     = (bf16*)(ws + 8400896);    // reused as att after gemm_qkv
  bf16*  q_buf  = (bf16*)(ws + 25178112);
  bf16*  k_buf  = (bf16*)(ws + 41955328);
  bf16*  v_buf  = (bf16*)(ws + 58732544);
  int*   flag   = (int*)(ws + 75509760);
  bf16*  att    = xc;

  // one-time: allow 128 KiB dynamic LDS (defensive; not a stream op, safe
  // under graph capture since it executes immediately and is persistent)
  static bool lds_attr_done = false;
  if (!lds_attr_done) {
    (void)hipFuncSetAttribute(reinterpret_cast<const void*>(gemm256_qkv),
                              hipFuncAttributeMaxDynamicSharedMemorySize, 131072);
    (void)hipFuncSetAttribute(reinterpret_cast<const void*>(gemm256_proj),
                              hipFuncAttributeMaxDynamicSharedMemorySize, 131072);
    lds_attr_done = true;
  }

  detect_dtype<<<1, 64, 0, stream>>>((const unsigned int*)x, flag);
  convert_x<<<4096, 256, 0, stream>>>(x, xc, flag);
  permute_wqkv<<<dim3(16, 16), 256, 0, stream>>>(w_qkv, b_qkv, wt_qkv, bqp, flag);
  transpose_wp<<<dim3(16, 16), 256, 0, stream>>>(w_proj, wtp, flag);
  gemm256_qkv<<<dim3(384), 512, 131072, stream>>>(xc, wt_qkv, bqp, q_buf, k_buf, v_buf);
  attn<<<dim3(8, 128), 256, 0, stream>>>(q_buf, k_buf, v_buf, att);
  gemm256_proj<<<dim3(128), 512, 131072, stream>>>(att, wtp, b_proj, out, flag);
}

// Round 2
// 270.239 us; speedup vs baseline: 1.1153x; 1.0694x over previous
//
#include <hip/hip_runtime.h>
#include <hip/hip_bf16.h>
#include <stdint.h>

typedef __hip_bfloat16 bf16;
typedef __attribute__((ext_vector_type(8))) short short8;
typedef __attribute__((ext_vector_type(4))) float f32x4;
typedef __attribute__((ext_vector_type(16))) float f32x16;

#define MFMA16(a, b, c) __builtin_amdgcn_mfma_f32_16x16x32_bf16(a, b, c, 0, 0, 0)
#define MFMA32(a, b, c) __builtin_amdgcn_mfma_f32_32x32x16_bf16(a, b, c, 0, 0, 0)

#define BATCH 8
#define SEQ   1024
#define DEMB  1024
#define NH    16
#define DH    64
#define MTOT  (BATCH * SEQ)   // 8192

// ---------------------------------------------------------------------------
// dtype helpers: flag==1 -> input buffers are float32; flag==0 -> bf16.
// ---------------------------------------------------------------------------
__device__ __forceinline__ float rdf(const void* p, size_t idx, int isf) {
  if (isf) return ((const float*)p)[idx];
  return __bfloat162float(((const bf16*)p)[idx]);
}

// pack two f32 -> bf16x2 dword
__device__ __forceinline__ unsigned int pk2(float a, float b) {
  unsigned short ua = __bfloat16_as_ushort(__float2bfloat16(a));
  unsigned short ub = __bfloat16_as_ushort(__float2bfloat16(b));
  return (unsigned int)ua | ((unsigned int)ub << 16);
}

union U4S8 { uint4 u; short8 s; };

// async global->LDS, 16B per lane; lds base wave-uniform (HW adds lane*16)
__device__ __forceinline__ void gload16(const bf16* g, bf16* l) {
  __builtin_amdgcn_global_load_lds(
      (const __attribute__((address_space(1))) void*)g,
      (__attribute__((address_space(3))) void*)l, 16, 0, 0);
}

// Kernel 0: detect input dtype from x.
__global__ void detect_dtype(const unsigned int* __restrict__ xw, int* __restrict__ flag) {
  int lane = threadIdx.x;  // 64 threads
  float v = __uint_as_float(xw[lane]);
  bool isf32 = (fabsf(v) < 1e20f);  // NaN/Inf -> false
  unsigned long long m = __ballot(isf32);
  if (lane == 0) flag[0] = (__popcll(m) >= 32) ? 1 : 0;
}

// Kernel 0b: canonicalize x -> bf16 xc[8192][1024]. 8 elems/thread.
__global__ __launch_bounds__(256) void convert_x(
    const void* __restrict__ xin, bf16* __restrict__ xc, const int* __restrict__ flag) {
  const int isf = flag[0];
  size_t i = ((size_t)blockIdx.x * 256 + threadIdx.x) * 8;
  if (isf) {
    const float* xf = (const float*)xin;
    float4 a = *(const float4*)&xf[i];
    float4 b = *(const float4*)&xf[i + 4];
    bf16 o[8];
    o[0] = __float2bfloat16(a.x); o[1] = __float2bfloat16(a.y);
    o[2] = __float2bfloat16(a.z); o[3] = __float2bfloat16(a.w);
    o[4] = __float2bfloat16(b.x); o[5] = __float2bfloat16(b.y);
    o[6] = __float2bfloat16(b.z); o[7] = __float2bfloat16(b.w);
    *(int4*)&xc[i] = *(const int4*)&o[0];
  } else {
    *(int4*)&xc[i] = *(const int4*)&((const bf16*)xin)[i];
  }
}

// ---------------------------------------------------------------------------
// Kernel 1: permute+transpose w_qkv -> wt [3072][1024]; bias -> f32 bqp.
// ---------------------------------------------------------------------------
__global__ __launch_bounds__(256) void permute_wqkv(
    const void* __restrict__ w, const void* __restrict__ b,
    bf16* __restrict__ wt, float* __restrict__ bqp, const int* __restrict__ flag) {
  __shared__ __attribute__((aligned(16))) bf16 ls[192][66];
  const int isf = flag[0];
  const int t = threadIdx.x;
  const int k0 = blockIdx.x * 64;
  const int h = blockIdx.y;
#pragma unroll
  for (int i = 0; i < 48; ++i) {
    int e = t + i * 256;
    int k = e / 192, c = e % 192;
    ls[c][k] = __float2bfloat16(rdf(w, (size_t)(k0 + k) * 3072 + h * 192 + c, isf));
  }
  if (blockIdx.x == 0 && t < 192) {
    int dd = t / 3, j = t % 3;
    bqp[j * 1024 + h * 64 + dd] = rdf(b, h * 192 + t, isf);
  }
  __syncthreads();
#pragma unroll
  for (int i = 0; i < 48; ++i) {
    int e = t + i * 256;
    int c = e / 64, k = e & 63;
    int dd = c / 3, j = c % 3;
    wt[(size_t)(j * 1024 + h * 64 + dd) * 1024 + k0 + k] = ls[c][k];
  }
}

// ---------------------------------------------------------------------------
// Kernel 2: transpose w_proj [1024][1024] -> wtp [n][k]
// ---------------------------------------------------------------------------
__global__ __launch_bounds__(256) void transpose_wp(
    const void* __restrict__ w, bf16* __restrict__ wt, const int* __restrict__ flag) {
  __shared__ __attribute__((aligned(16))) bf16 ls[64][66];
  const int isf = flag[0];
  const int t = threadIdx.x;
  const int r0 = blockIdx.y * 64;
  const int c0 = blockIdx.x * 64;
#pragma unroll
  for (int i = 0; i < 16; ++i) {
    int e = t + i * 256;
    int r = e >> 6, c = e & 63;
    ls[c][r] = __float2bfloat16(rdf(w, (size_t)(r0 + r) * 1024 + c0 + c, isf));
  }
  __syncthreads();
#pragma unroll
  for (int i = 0; i < 16; ++i) {
    int e = t + i * 256;
    int c = e >> 6, r = e & 63;
    wt[(size_t)(c0 + c) * 1024 + r0 + r] = ls[c][r];
  }
}

// ---------------------------------------------------------------------------
// LDS bank swizzle (T2), BK=32 rows = 64B:
//   16B-slot s_phys = quad ^ ((row>>1)&3)  <=>  byte ^= ((byte>>6)&3)<<4.
// Writes stay LINEAR (global_load_lds); the GLOBAL source column is
// pre-permuted with the same involution (rule #21: both-sides-or-neither;
// content: LDS[y] = G[swz(y)], reader at swz(lin) returns G[lin]).
// Bank check: any 8 consecutive lanes of a frag read now cover all 8
// 4-bank groups exactly once (was 2 groups 4x each -> ~32 extra cyc/read,
// = the measured 4.7M conflicts).
// ---------------------------------------------------------------------------

// ---------------------------------------------------------------------------
// 256x256 deep-pipelined GEMM core. BK=32, 4-slot LDS ring (128 KiB).
// 8 waves (2M x 4N), per-wave C = 128x64 = acc[8][4].
// Per K-tile: 2 phases x {ds_read frags; 2 gload_lds for tile tau+3;
// barrier; lgkmcnt(0); setprio(1); 16 MFMA; setprio(0); barrier}.
// vmcnt(8) once per K-tile boundary (12 in flight -> drain tau+1's 4).
// ---------------------------------------------------------------------------
__device__ __forceinline__ void gemm256_core(
    const bf16* __restrict__ A, const bf16* __restrict__ Bt,
    int m0, int n0, bf16* lds, f32x4 acc[8][4]) {
  const int t = threadIdx.x;
  const int lane = t & 63, w = t >> 6;
  const int l15 = lane & 15, quad = lane >> 4;
  const int wm = w >> 2, wn = w & 3;

  // staging: lane covers row (lane>>2) of its wave's 16-row subtile;
  // source 16B-chunk pre-swizzled: scs = ((lane&3) ^ ((lane>>3)&3))*8 elems
  const int sr = lane >> 2;
  const int scs = (((lane & 3) ^ ((lane >> 3) & 3))) * 8;
  const bf16* gA = A + (size_t)(m0 + w * 16 + sr) * 1024 + scs;
  const bf16* gB = Bt + (size_t)(n0 + w * 16 + sr) * 1024 + scs;

  // prologue: stage K-tiles 0,1,2 into slots 0,1,2
#pragma unroll
  for (int tt = 0; tt < 3; ++tt) {
    bf16* sb = lds + tt * 16384;
    gload16(gA + tt * 32, sb + w * 512);
    gload16(gA + tt * 32 + 131072, sb + 4096 + w * 512);
    gload16(gB + tt * 32, sb + 8192 + w * 512);
    gload16(gB + tt * 32 + 131072, sb + 12288 + w * 512);
  }
  asm volatile("s_waitcnt vmcnt(8)" ::: "memory");  // tile 0 landed; 1,2 in flight
  __builtin_amdgcn_s_barrier();

  // swizzled read bases (row bits [2:1] = l15 bits [2:1], invariant over fi/fj)
  const int swz8 = ((quad ^ (l15 >> 1)) & 3) * 8;
  const bf16* paBase = lds + (wm * 128 + l15) * 32 + swz8;
  const bf16* pbBase = lds + 8192 + (wn * 64 + l15) * 32 + swz8;

#pragma unroll 4
  for (int tau = 0; tau < 32; ++tau) {
    const int slot = tau & 3;
    const int pf = (tau + 3) & 3;                 // slot freed at end of tau-1
    const int kpf = ((tau + 3) & 31) * 32;        // wrap tail prefetch in-bounds
    const bf16* pa0 = paBase + slot * 16384;
    const bf16* pb0 = pbBase + slot * 16384;
    bf16* sb = lds + pf * 16384;

    short8 afr[4], bfr[4];
    // ---- phase 0: fi 0..3, all fj ----
#pragma unroll
    for (int i = 0; i < 4; ++i) afr[i] = *(const short8*)(pa0 + i * 512);
#pragma unroll
    for (int j = 0; j < 4; ++j) bfr[j] = *(const short8*)(pb0 + j * 512);
    gload16(gA + kpf, sb + w * 512);
    gload16(gA + kpf + 131072, sb + 4096 + w * 512);
    asm volatile("" ::: "memory");
    __builtin_amdgcn_s_barrier();
    asm volatile("s_waitcnt lgkmcnt(0)" ::: "memory");
    __builtin_amdgcn_s_setprio(1);
#pragma unroll
    for (int i = 0; i < 4; ++i)
#pragma unroll
      for (int j = 0; j < 4; ++j)
        acc[i][j] = MFMA16(afr[i], bfr[j], acc[i][j]);
    __builtin_amdgcn_s_setprio(0);
    asm volatile("" ::: "memory");
    __builtin_amdgcn_s_barrier();

    // ---- phase 1: fi 4..7, reuse bfr ----
    const bf16* pa1 = pa0 + 64 * 32;
#pragma unroll
    for (int i = 0; i < 4; ++i) afr[i] = *(const short8*)(pa1 + i * 512);
    gload16(gB + kpf, sb + 8192 + w * 512);
    gload16(gB + kpf + 131072, sb + 12288 + w * 512);
    asm volatile("" ::: "memory");
    __builtin_amdgcn_s_barrier();
    asm volatile("s_waitcnt lgkmcnt(0)" ::: "memory");
    __builtin_amdgcn_s_setprio(1);
#pragma unroll
    for (int i = 0; i < 4; ++i)
#pragma unroll
      for (int j = 0; j < 4; ++j)
        acc[4 + i][j] = MFMA16(afr[i], bfr[j], acc[4 + i][j]);
    __builtin_amdgcn_s_setprio(0);
    asm volatile("s_waitcnt vmcnt(8)" ::: "memory");  // K-tile boundary: tau+1 landed
    asm volatile("" ::: "memory");
    __builtin_amdgcn_s_barrier();
  }
  asm volatile("s_waitcnt vmcnt(0)" ::: "memory");    // drain before epilogue loads
}

// ---------------------------------------------------------------------------
// 128x256 core (for proj: grid must be 256 exactly). BK=32, 4-slot ring,
// slot = A[128][32] @0 + B[256][32] @4096 el = 24 KiB; 4 slots = 96 KiB.
// 8 waves 2M x 4N, per-wave C = 64x64 = acc[4][4]. One 16-MFMA phase per
// K-tile; 3 gloads/wave/tau; counted vmcnt(6) (9 in flight at issue).
// ---------------------------------------------------------------------------
__device__ __forceinline__ void gemm128x256_core(
    const bf16* __restrict__ A, const bf16* __restrict__ Bt,
    int m0, int n0, bf16* lds, f32x4 acc[4][4]) {
  const int t = threadIdx.x;
  const int lane = t & 63, w = t >> 6;
  const int l15 = lane & 15, quad = lane >> 4;
  const int wm = w >> 2, wn = w & 3;
  const int sr = lane >> 2;
  const int scs = (((lane & 3) ^ ((lane >> 3) & 3))) * 8;
  const bf16* gA = A + (size_t)(m0 + w * 16 + sr) * 1024 + scs;
  const bf16* gB = Bt + (size_t)(n0 + w * 16 + sr) * 1024 + scs;

#pragma unroll
  for (int tt = 0; tt < 3; ++tt) {
    bf16* sb = lds + tt * 12288;
    gload16(gA + tt * 32, sb + w * 512);
    gload16(gB + tt * 32, sb + 4096 + w * 512);
    gload16(gB + tt * 32 + 131072, sb + 8192 + w * 512);
  }
  asm volatile("s_waitcnt vmcnt(6)" ::: "memory");  // tile 0 landed
  __builtin_amdgcn_s_barrier();

  const int swz8 = ((quad ^ (l15 >> 1)) & 3) * 8;
  const bf16* paBase = lds + (wm * 64 + l15) * 32 + swz8;
  const bf16* pbBase = lds + 4096 + (wn * 64 + l15) * 32 + swz8;

#pragma unroll 4
  for (int tau = 0; tau < 32; ++tau) {
    const int slot = tau & 3;
    const int pf = (tau + 3) & 3;
    const int kpf = ((tau + 3) & 31) * 32;
    const bf16* pa = paBase + slot * 12288;
    const bf16* pb = pbBase + slot * 12288;
    bf16* sb = lds + pf * 12288;
    short8 afr[4], bfr[4];
#pragma unroll
    for (int i = 0; i < 4; ++i) afr[i] = *(const short8*)(pa + i * 512);
#pragma unroll
    for (int j = 0; j < 4; ++j) bfr[j] = *(const short8*)(pb + j * 512);
    gload16(gA + kpf, sb + w * 512);
    gload16(gB + kpf, sb + 4096 + w * 512);
    gload16(gB + kpf + 131072, sb + 8192 + w * 512);
    asm volatile("" ::: "memory");
    __builtin_amdgcn_s_barrier();
    asm volatile("s_waitcnt lgkmcnt(0)" ::: "memory");
    __builtin_amdgcn_s_setprio(1);
#pragma unroll
    for (int i = 0; i < 4; ++i)
#pragma unroll
      for (int j = 0; j < 4; ++j)
        acc[i][j] = MFMA16(afr[i], bfr[j], acc[i][j]);
    __builtin_amdgcn_s_setprio(0);
    asm volatile("s_waitcnt vmcnt(6)" ::: "memory");  // tau+1 landed
    asm volatile("" ::: "memory");
    __builtin_amdgcn_s_barrier();
  }
  asm volatile("s_waitcnt vmcnt(0)" ::: "memory");
}

// ---------------------------------------------------------------------------
// Kernel 3: QKV GEMM (256^2 core). Scatters q,k -> [b][h][n][dd]; v -> [b][h][dd][n].
// grid 384 = (8192/256) x (3072/256), XCD-bijective swizzle (384 % 8 == 0).
// ---------------------------------------------------------------------------
__global__ __launch_bounds__(512, 2) void gemm256_qkv(
    const bf16* __restrict__ A, const bf16* __restrict__ Bt,
    const float* __restrict__ bias,
    bf16* __restrict__ qb, bf16* __restrict__ kb, bf16* __restrict__ vb) {
  extern __shared__ bf16 smem[];
  const int t = threadIdx.x;
  const int lane = t & 63;
  const int l15 = lane & 15, quad = lane >> 4;
  const int w = t >> 6, wm = w >> 2, wn = w & 3;
  const int bid = blockIdx.x;
  const int swz = (bid & 7) * 48 + (bid >> 3);   // 384/8 = 48 per XCD
  const int m0 = (swz / 12) * 256;
  const int n0 = (swz % 12) * 256;

  f32x4 acc[8][4];
  const f32x4 zero = {0.f, 0.f, 0.f, 0.f};
#pragma unroll
  for (int i = 0; i < 8; ++i)
#pragma unroll
    for (int j = 0; j < 4; ++j) acc[i][j] = zero;

  gemm256_core(A, Bt, m0, n0, smem, acc);

  const int jj = n0 >> 10;                       // 0=q 1=k 2=v (256-tile within chunk)
  const int hh = ((n0 + wn * 64) & 1023) >> 6;   // head: uniform per wave
#pragma unroll
  for (int fi = 0; fi < 8; ++fi) {
    int m = m0 + wm * 128 + fi * 16 + quad * 4;
    int bb = m >> 10, nidx = m & 1023;
    size_t bhq = (size_t)(bb * NH + hh);
#pragma unroll
    for (int fj = 0; fj < 4; ++fj) {
      int dd = fj * 16 + l15;
      float bv = bias[n0 + wn * 64 + dd];
      if (jj == 2) {
        // v: [b][h][dd][n] -> 4 consecutive n pack into 8B
        unsigned int lo = pk2(acc[fi][fj][0] + bv, acc[fi][fj][1] + bv);
        unsigned int hi = pk2(acc[fi][fj][2] + bv, acc[fi][fj][3] + bv);
        *(uint2*)&vb[(bhq * 64 + dd) * 1024 + nidx] = make_uint2(lo, hi);
      } else {
        bf16* dst = (jj == 0) ? qb : kb;
#pragma unroll
        for (int r = 0; r < 4; ++r)
          dst[(bhq * 1024 + (size_t)(nidx + r)) * 64 + dd] =
              __float2bfloat16(acc[fi][fj][r] + bv);
      }
    }
  }
}

// ---------------------------------------------------------------------------
// Kernel 4 v2: flash attention with 32x32x16 MFMA, S^T/O^T formulation.
// ---------------------------------------------------------------------------
__global__ __launch_bounds__(256, 4) void attn(
    const bf16* __restrict__ qb, const bf16* __restrict__ kb,
    const bf16* __restrict__ vb, bf16* __restrict__ ob) {
  const int t = threadIdx.x, lane = t & 63, w = t >> 6;
  const int q5 = lane & 31, half = lane >> 5;
  const int bh = blockIdx.y;
  const int bat = bh >> 4, h = bh & 15;
  const int q0 = blockIdx.x * 128;
  const int qrow = q0 + w * 32 + q5;

  __shared__ __attribute__((aligned(16))) bf16 lsK[64][72];  // 9216 B
  __shared__ __attribute__((aligned(16))) bf16 lsV[64][72];  // 9216 B

  const bf16* qp = qb + (size_t)bh * (1024 * 64);
  const bf16* kp = kb + (size_t)bh * (1024 * 64);
  const bf16* vp = vb + (size_t)bh * (64 * 1024);  // [dv][n]

  short8 bq[4];
#pragma unroll
  for (int kk = 0; kk < 4; ++kk)
    bq[kk] = *(const short8*)&qp[(size_t)qrow * 64 + kk * 16 + half * 8];

  float m_run = -1e30f, l_run = 0.f;
  f32x16 po[2];
#pragma unroll
  for (int r = 0; r < 16; ++r) { po[0][r] = 0.f; po[1][r] = 0.f; }

  const int sr = t >> 3;        // 0..31
  const int sc = (t & 7) * 8;   // 0..56

  for (int kt = 0; kt < 1024; kt += 64) {
    int4 g0 = *(const int4*)&kp[(size_t)(kt + sr) * 64 + sc];
    int4 g1 = *(const int4*)&kp[(size_t)(kt + 32 + sr) * 64 + sc];
    int4 g2 = *(const int4*)&vp[(size_t)sr * 1024 + kt + sc];
    int4 g3 = *(const int4*)&vp[(size_t)(32 + sr) * 1024 + kt + sc];
    __syncthreads();
    *(int4*)&lsK[sr][sc] = g0;
    *(int4*)&lsK[32 + sr][sc] = g1;
    *(int4*)&lsV[sr][sc] = g2;
    *(int4*)&lsV[32 + sr][sc] = g3;
    __syncthreads();

    f32x16 st[2];
#pragma unroll
    for (int r = 0; r < 16; ++r) { st[0][r] = 0.f; st[1][r] = 0.f; }
#pragma unroll
    for (int kk = 0; kk < 4; ++kk) {
#pragma unroll
      for (int tj = 0; tj < 2; ++tj) {
        short8 ak = *(const short8*)&lsK[tj * 32 + q5][kk * 16 + half * 8];
        st[tj] = MFMA32(ak, bq[kk], st[tj]);
      }
    }

    float smax = st[0][0];
#pragma unroll
    for (int r = 1; r < 16; ++r) smax = fmaxf(smax, st[0][r]);
#pragma unroll
    for (int r = 0; r < 16; ++r) smax = fmaxf(smax, st[1][r]);
    smax = fmaxf(smax, __shfl_xor(smax, 32));
    float mnew = fmaxf(m_run, smax);
    float alpha = __expf(m_run - mnew);
    m_run = mnew;
    float lsum = 0.f;
#pragma unroll
    for (int tj = 0; tj < 2; ++tj)
#pragma unroll
      for (int r = 0; r < 16; ++r) {
        float p = __expf(st[tj][r] - mnew);
        st[tj][r] = p;
        lsum += p;
      }
    lsum += __shfl_xor(lsum, 32);
    l_run = l_run * alpha + lsum;
#pragma unroll
    for (int r = 0; r < 16; ++r) { po[0][r] *= alpha; po[1][r] *= alpha; }

#pragma unroll
    for (int kk2 = 0; kk2 < 4; ++kk2) {
      const int nbA = 2 * kk2, nbB = 2 * kk2 + 1;
      unsigned int a0 = pk2(st[nbA >> 2][4 * (nbA & 3) + 0], st[nbA >> 2][4 * (nbA & 3) + 1]);
      unsigned int a1 = pk2(st[nbA >> 2][4 * (nbA & 3) + 2], st[nbA >> 2][4 * (nbA & 3) + 3]);
      unsigned int b0 = pk2(st[nbB >> 2][4 * (nbB & 3) + 0], st[nbB >> 2][4 * (nbB & 3) + 1]);
      unsigned int b1 = pk2(st[nbB >> 2][4 * (nbB & 3) + 2], st[nbB >> 2][4 * (nbB & 3) + 3]);
      unsigned int s0 = half ? a0 : b0;
      unsigned int s1 = half ? a1 : b1;
      unsigned int r0 = (unsigned int)__shfl_xor((int)s0, 32);
      unsigned int r1 = (unsigned int)__shfl_xor((int)s1, 32);
      U4S8 fr;
      fr.u.x = half ? r0 : a0;
      fr.u.y = half ? r1 : a1;
      fr.u.z = half ? b0 : r0;
      fr.u.w = half ? b1 : r1;
#pragma unroll
      for (int ti = 0; ti < 2; ++ti) {
        short8 av = *(const short8*)&lsV[ti * 32 + q5][kk2 * 16 + half * 8];
        po[ti] = MFMA32(av, fr.s, po[ti]);
      }
    }
  }

  float inv = 1.0f / (l_run * 32.0f);
  bf16* op = ob + ((size_t)(bat * 1024 + qrow)) * 1024 + h * 64;
#pragma unroll
  for (int ti = 0; ti < 2; ++ti)
#pragma unroll
    for (int g = 0; g < 4; ++g) {
      unsigned int lo = pk2(po[ti][4 * g + 0] * inv, po[ti][4 * g + 1] * inv);
      unsigned int hi = pk2(po[ti][4 * g + 2] * inv, po[ti][4 * g + 3] * inv);
      uint2 u = make_uint2(lo, hi);
      *(uint2*)&op[ti * 32 + g * 8 + half * 4] = u;
    }
}

// ---------------------------------------------------------------------------
// Kernel 5: output projection (128x256 core). OUTPUT: float32.
// grid 256 = (8192/128) x (1024/256) exactly 1 block/CU; XCD swizzle.
// ---------------------------------------------------------------------------
__global__ __launch_bounds__(512, 2) void gemm256_proj(
    const bf16* __restrict__ A, const bf16* __restrict__ Bt,
    const void* __restrict__ bias, float* __restrict__ out,
    const int* __restrict__ flag) {
  extern __shared__ bf16 smem[];
  const int t = threadIdx.x;
  const int lane = t & 63;
  const int l15 = lane & 15, quad = lane >> 4;
  const int w = t >> 6, wm = w >> 2, wn = w & 3;
  const int bid = blockIdx.x;
  const int swz = (bid & 7) * 32 + (bid >> 3);   // 256/8 = 32 per XCD
  const int m0 = (swz >> 2) * 128;               // 64 m-tiles
  const int n0 = (swz & 3) * 256;                // 4 n-tiles

  f32x4 acc[4][4];
  const f32x4 zero = {0.f, 0.f, 0.f, 0.f};
#pragma unroll
  for (int i = 0; i < 4; ++i)
#pragma unroll
    for (int j = 0; j < 4; ++j) acc[i][j] = zero;

  gemm128x256_core(A, Bt, m0, n0, smem, acc);

  const int isf = flag[0];
#pragma unroll
  for (int fj = 0; fj < 4; ++fj) {
    int c = n0 + wn * 64 + fj * 16 + l15;
    float bv = rdf(bias, c, isf);
#pragma unroll
    for (int fi = 0; fi < 4; ++fi) {
      int m = m0 + wm * 64 + fi * 16 + quad * 4;
#pragma unroll
      for (int r = 0; r < 4; ++r)
        out[(size_t)(m + r) * 1024 + c] = acc[fi][fj][r] + bv;
    }
  }
}

// ---------------------------------------------------------------------------
// Launcher. ws layout (75.5 MB):
//   wt_qkv 6MB | bqp 12KB | wtp 2MB | xc/att 16MB | q 16MB | k 16MB | v 16MB | flag
// ---------------------------------------------------------------------------
extern "C" void kernel_launch(void* const* d_in, const int* in_sizes, int n_in,
                              void* d_out, int out_size, void* d_ws, size_t ws_size,
                              hipStream_t stream) {
  const void* x      = d_in[0];
  const void* w_qkv  = d_in[1];
  const void* b_qkv  = d_in[2];
  const void* w_proj = d_in[3];
  const void* b_proj = d_in[4];
  float* out = (float*)d_out;

  char* ws = (char*)d_ws;
  bf16*  wt_qkv = (bf16*)(ws);
  float* bqp    = (float*)(ws + 6291456);
  bf16*  wtp    = (bf16*)(ws + 6303744);
  bf16*  xc     = (bf16*)(ws + 8400896);    // reused as att after gemm_qkv
  bf16*  q_buf  = (bf16*)(ws + 25178112);
  bf16*  k_buf  = (bf16*)(ws + 41955328);
  bf16*  v_buf  = (bf16*)(ws + 58732544);
  int*   flag   = (int*)(ws + 75509760);
  bf16*  att    = xc;

  static bool lds_attr_done = false;
  if (!lds_attr_done) {
    (void)hipFuncSetAttribute(reinterpret_cast<const void*>(gemm256_qkv),
                              hipFuncAttributeMaxDynamicSharedMemorySize, 131072);
    (void)hipFuncSetAttribute(reinterpret_cast<const void*>(gemm256_proj),
                              hipFuncAttributeMaxDynamicSharedMemorySize, 131072);
    lds_attr_done = true;
  }

  detect_dtype<<<1, 64, 0, stream>>>((const unsigned int*)x, flag);
  convert_x<<<4096, 256, 0, stream>>>(x, xc, flag);
  permute_wqkv<<<dim3(16, 16), 256, 0, stream>>>(w_qkv, b_qkv, wt_qkv, bqp, flag);
  transpose_wp<<<dim3(16, 16), 256, 0, stream>>>(w_proj, wtp, flag);
  gemm256_qkv<<<dim3(384), 512, 131072, stream>>>(xc, wt_qkv, bqp, q_buf, k_buf, v_buf);
  attn<<<dim3(8, 128), 256, 0, stream>>>(q_buf, k_buf, v_buf, att);
  gemm256_proj<<<dim3(256), 512, 98304, stream>>>(att, wtp, b_proj, out, flag);
}